// Round 8
// baseline (3306.898 us; speedup 1.0000x reference)
//
#include <hip/hip_runtime.h>
#include <hip/hip_bf16.h>

#define N_USERS 100000
#define E_HYPER 50000
#define NNZ_E   800000
#define T_STEPS 8
#define DIM     64

#define CAP_E   48
#define CAP_N   36

#define TR_BLOCKS  1024
#define GE_BLOCKS  1563
#define GNF_BLOCKS 1563
#define ZERO_BLKS  147

#define SC_PARTS   8
#define SC_SUB     256
#define SC_BLOCKS  (SC_PARTS * SC_SUB)   // 2048
#define SC_CHUNK   (NNZ_E / SC_SUB)      // 3125
#define E_SLICE    (E_HYPER / SC_PARTS)  // 6250
#define N_SLICE    (N_USERS / SC_PARTS)  // 12500

// interleave geometry: groups of 8 bids; even group -> primary, odd -> append.
// preserves part = b&7 (XCD identity) for append's write locality (R3-proven).
#define GA_GROUPS  196   // ceil(1563/8)
#define AP_GROUPS  256   // 2048/8
#define MAIN_BLKS  ((GA_GROUPS + AP_GROUPS) * 8)   // 3616
#define TR_GROUPS  128   // 1024/8
#define PRO_BLKS   ((TR_GROUPS + AP_GROUPS) * 8)   // 3072

typedef __bf16 bf16x8 __attribute__((ext_vector_type(8)));
typedef float  f32x4  __attribute__((ext_vector_type(4)));

// ---------------------------------------------------------------------------
__device__ __forceinline__ float ld_in(const void* p, size_t i, int f32)
{
    return f32 ? ((const float*)p)[i]
               : __bfloat162float(((const __hip_bfloat16*)p)[i]);
}

__device__ __forceinline__ void st_carry(void* out, float* cws, size_t i,
                                         int f, int use_ws, float v)
{
    if (f) { ((float*)out)[i] = v; return; }
    if (use_ws) { cws[i] = v; return; }
    ((__hip_bfloat16*)out)[i] = __float2bfloat16(v);
}

// ---------------------------------------------------------------------------
// Kernel 0: input dtype detector
// ---------------------------------------------------------------------------
__global__ void k_detect(const unsigned short* __restrict__ raw, int* __restrict__ flag)
{
    __shared__ int cnt;
    if (threadIdx.x == 0) cnt = 0;
    __syncthreads();
    int c = 0;
    for (int i = threadIdx.x; i < 4096; i += blockDim.x) {
        int e = (raw[i] >> 7) & 0xFF;
        if (e > 126) c++;
    }
    atomicAdd(&cnt, c);
    __syncthreads();
    if (threadIdx.x == 0) *flag = (cnt > 64) ? 1 : 0;
}

// ---------------------------------------------------------------------------
// Kernel 0b: params -> fp32 staging
// st: W[0,4096) b[4096,4160) w1[4160,8256) b1[8256,8320) w2[8320,8384) b2[8384]
// ---------------------------------------------------------------------------
__global__ void k_convert_params(
    const void* W, const void* b, const void* w1, const void* b1,
    const void* w2, const void* b2, const int* __restrict__ flag,
    float* __restrict__ st)
{
    int f = *flag;
    int i = blockIdx.x * blockDim.x + threadIdx.x;
    if (i < 4096)          st[i] = ld_in(W,  i,        f);
    else if (i < 4160)     st[i] = ld_in(b,  i - 4096, f);
    else if (i < 8256)     st[i] = ld_in(w1, i - 4160, f);
    else if (i < 8320)     st[i] = ld_in(b1, i - 8256, f);
    else if (i < 8384)     st[i] = ld_in(w2, i - 8320, f);
    else if (i == 8384)    st[i] = ld_in(b2, 0,        f);
}

// ---------------------------------------------------------------------------
// Padded atomic-append. counts slab: [0,E_HYPER) per-hyperedge,
// [E_HYPER,+N_USERS) per-node. part = b&7 (XCD proxy), sub = append group.
// ---------------------------------------------------------------------------
__device__ __forceinline__ void appendE_body(
    const int* __restrict__ nodes, const int* __restrict__ hyper,
    int* __restrict__ cnt, int* __restrict__ sn_pad, int part, int sub, int tid)
{
    int elo = part * E_SLICE;
    int i0  = sub * SC_CHUNK;
    for (int i = i0 + tid; i < i0 + SC_CHUNK; i += 256) {
        int hy = hyper[i];
        if ((unsigned)(hy - elo) < (unsigned)E_SLICE) {
            int r = atomicAdd(&cnt[hy], 1);
            if (r < CAP_E) sn_pad[hy * CAP_E + r] = nodes[i];
        }
    }
}

__device__ __forceinline__ void appendN_body(
    const int* __restrict__ nodes, const int* __restrict__ hyper,
    int* __restrict__ cnt, int* __restrict__ sh_pad, int part, int sub, int tid)
{
    int nlo = part * N_SLICE;
    int i0  = sub * SC_CHUNK;
    for (int i = i0 + tid; i < i0 + SC_CHUNK; i += 256) {
        int nd = nodes[i];
        if ((unsigned)(nd - nlo) < (unsigned)N_SLICE) {
            int r = atomicAdd(&cnt[E_HYPER + nd], 1);
            if (r < CAP_N) sh_pad[nd * CAP_N + r] = hyper[i];
        }
    }
}

__device__ __forceinline__ void zero_body(int* __restrict__ buf, int b, int tid)
{
    int idx = b * 256 + tid;
    if (idx < 150000 / 4) ((int4*)buf)[idx] = make_int4(0, 0, 0, 0);
}

// ---------------------------------------------------------------------------
// gather_e body (padded CSR, 8 segments/wave)
// ---------------------------------------------------------------------------
__device__ __forceinline__ void ge_body(
    const __hip_bfloat16* __restrict__ h,
    const int* __restrict__ sn_pad, const int* __restrict__ cnt_e,
    __hip_bfloat16* __restrict__ e, int bid, int tid)
{
    int lane = tid & 63;
    int wid = bid * 4 + (tid >> 6);
    int nW  = GE_BLOCKS * 4;
    for (int s0 = wid * 8; s0 < E_HYPER; s0 += nW * 8) {
        int pos[8], end8[8], cnt8[8]; float acc[8];
#pragma unroll
        for (int c = 0; c < 8; ++c) {
            int sg = s0 + c;
            int cc = (sg < E_HYPER) ? cnt_e[sg] : 0;
            cnt8[c] = cc;
            pos[c]  = sg * CAP_E;
            end8[c] = pos[c] + min(cc, CAP_E);
            acc[c]  = 0.f;
        }
        while (true) {
            bool any = false;
#pragma unroll
            for (int c = 0; c < 8; ++c) any = any || (pos[c] < end8[c]);
            if (!any) break;
            int id[8];
#pragma unroll
            for (int c = 0; c < 8; ++c)
                if (pos[c] < end8[c]) id[c] = sn_pad[pos[c]];
#pragma unroll
            for (int c = 0; c < 8; ++c)
                if (pos[c] < end8[c]) {
                    acc[c] += __bfloat162float(h[(size_t)id[c] * DIM + lane]);
                    pos[c]++;
                }
        }
#pragma unroll
        for (int c = 0; c < 8; ++c) {
            int sg = s0 + c;
            if (sg < E_HYPER)
                e[(size_t)sg * DIM + lane] =
                    __float2bfloat16(acc[c] / (float)max(cnt8[c], 1));
        }
    }
}

// ---------------------------------------------------------------------------
// fuse tile: ONE 16-row tile at rows [row0,row0+16), dy from LDS (stride 68)
// ---------------------------------------------------------------------------
__device__ __forceinline__ void fu_tile(
    void* __restrict__ dout, float* __restrict__ cws,
    const float* __restrict__ dyl_t, const float* __restrict__ st,
    int f, int use_ws, int write_out, int row0, int tid)
{
    float* cf = f ? (float*)dout : (use_ws ? cws : (float*)0);
    __hip_bfloat16* cb = (__hip_bfloat16*)dout;

    int lane = tid & 63;
    int quad = lane >> 4;
    int m    = lane & 15;

    bf16x8 bw[4][2];
    float b1v[4], w2v[4];
#pragma unroll
    for (int nt = 0; nt < 4; ++nt) {
#pragma unroll
        for (int kb = 0; kb < 2; ++kb)
#pragma unroll
            for (int j = 0; j < 8; ++j) {
                int k = kb * 32 + quad * 8 + j;
                bw[nt][kb][j] = (__bf16)st[4160 + k * 64 + nt * 16 + m];
            }
        b1v[nt] = st[8256 + nt * 16 + m];
        w2v[nt] = st[8320 + nt * 16 + m];
    }

    int row = row0 + m;
    size_t base = (size_t)row * DIM;

    float hidf[2][8], dyf[2][8];
    const f32x4* dp = (const f32x4*)(dyl_t + m * 68);
    if (cf) {
        const f32x4* cp = (const f32x4*)(cf + base);
#pragma unroll
        for (int kb = 0; kb < 2; ++kb) {
            f32x4 a = cp[kb * 8 + quad * 2], b = cp[kb * 8 + quad * 2 + 1];
            f32x4 c = dp[kb * 8 + quad * 2], d = dp[kb * 8 + quad * 2 + 1];
#pragma unroll
            for (int j = 0; j < 4; ++j) {
                hidf[kb][j] = a[j]; hidf[kb][4 + j] = b[j];
                dyf[kb][j]  = c[j]; dyf[kb][4 + j]  = d[j];
            }
        }
    } else {
#pragma unroll
        for (int kb = 0; kb < 2; ++kb)
#pragma unroll
            for (int j = 0; j < 8; ++j) {
                int k = kb * 32 + quad * 8 + j;
                hidf[kb][j] = __bfloat162float(cb[base + k]);
                dyf[kb][j]  = dyl_t[m * 68 + k];
            }
    }

    bf16x8 ah[2], ad[2];
#pragma unroll
    for (int kb = 0; kb < 2; ++kb)
#pragma unroll
        for (int j = 0; j < 8; ++j) {
            ah[kb][j] = (__bf16)hidf[kb][j];
            ad[kb][j] = (__bf16)dyf[kb][j];
        }

    float zh[4] = {0.f, 0.f, 0.f, 0.f};
    float zd[4] = {0.f, 0.f, 0.f, 0.f};
#pragma unroll
    for (int nt = 0; nt < 4; ++nt) {
        f32x4 acch = {0.f, 0.f, 0.f, 0.f};
        f32x4 accd = {0.f, 0.f, 0.f, 0.f};
#pragma unroll
        for (int kb = 0; kb < 2; ++kb) {
            acch = __builtin_amdgcn_mfma_f32_16x16x32_bf16(ah[kb], bw[nt][kb], acch, 0, 0, 0);
            accd = __builtin_amdgcn_mfma_f32_16x16x32_bf16(ad[kb], bw[nt][kb], accd, 0, 0, 0);
        }
#pragma unroll
        for (int reg = 0; reg < 4; ++reg) {
            zh[reg] += tanhf(acch[reg] + b1v[nt]) * w2v[nt];
            zd[reg] += tanhf(accd[reg] + b1v[nt]) * w2v[nt];
        }
    }
    float s[4];
#pragma unroll
    for (int reg = 0; reg < 4; ++reg) {
#pragma unroll
        for (int off = 1; off < 16; off <<= 1) {
            zh[reg] += __shfl_xor(zh[reg], off, 64);
            zd[reg] += __shfl_xor(zd[reg], off, 64);
        }
        float mm = fmaxf(zh[reg], zd[reg]);
        float eh = expf(zh[reg] - mm), ed = expf(zd[reg] - mm);
        s[reg] = eh / (eh + ed);
    }
    int srcl = (m >> 2) * 16;
    float s0 = __shfl(s[0], srcl, 64), s1 = __shfl(s[1], srcl, 64);
    float s2 = __shfl(s[2], srcl, 64), s3 = __shfl(s[3], srcl, 64);
    int r3 = m & 3;
    float sv = (r3 == 0) ? s0 : (r3 == 1) ? s1 : (r3 == 2) ? s2 : s3;

    if (cf) {
        f32x4* cp = (f32x4*)(cf + base);
#pragma unroll
        for (int kb = 0; kb < 2; ++kb) {
            f32x4 v0, v1;
#pragma unroll
            for (int j = 0; j < 4; ++j) {
                v0[j] = sv * hidf[kb][j]     + (1.f - sv) * dyf[kb][j];
                v1[j] = sv * hidf[kb][4 + j] + (1.f - sv) * dyf[kb][4 + j];
            }
            cp[kb * 8 + quad * 2]     = v0;
            cp[kb * 8 + quad * 2 + 1] = v1;
            if (write_out && !f) {
#pragma unroll
                for (int j = 0; j < 4; ++j) {
                    int k = kb * 32 + quad * 8 + j;
                    cb[base + k]     = __float2bfloat16(v0[j]);
                    cb[base + k + 4] = __float2bfloat16(v1[j]);
                }
            }
        }
    } else {
#pragma unroll
        for (int kb = 0; kb < 2; ++kb)
#pragma unroll
            for (int j = 0; j < 8; ++j) {
                int k = kb * 32 + quad * 8 + j;
                float v = sv * hidf[kb][j] + (1.f - sv) * dyf[kb][j];
                cb[base + k] = __float2bfloat16(v);
            }
    }
}

// ---------------------------------------------------------------------------
// Prologue: zero counts slabs 0 and 1
// ---------------------------------------------------------------------------
__global__ __launch_bounds__(256) void k_zero2(int* __restrict__ c0, int* __restrict__ c1)
{
    if ((int)blockIdx.x < ZERO_BLKS) zero_body(c0, blockIdx.x, threadIdx.x);
    else                             zero_body(c1, blockIdx.x - ZERO_BLKS, threadIdx.x);
}

// ---------------------------------------------------------------------------
// Prologue: transform INTERLEAVED with append-E(0)
// ---------------------------------------------------------------------------
__global__ __launch_bounds__(256) void k_trans_appendE(
    const void* __restrict__ emb, const int* __restrict__ flag,
    const float* __restrict__ st, __hip_bfloat16* __restrict__ h,
    const int* __restrict__ nodes, const int* __restrict__ hyper,
    int* __restrict__ cnt, int* __restrict__ sn_pad)
{
    __shared__ float Wl[DIM * DIM];
    __shared__ float bl[DIM];
    int b = blockIdx.x, tid = threadIdx.x;
    int g = b >> 3, l8 = b & 7;
    int role, idx;
    if (g < 2 * TR_GROUPS) { role = g & 1; idx = g >> 1; }
    else { role = 1; idx = g - TR_GROUPS; }

    if (role == 0) {
        int tb = idx * 8 + l8;   // 0..1023
        for (int i = tid; i < DIM * DIM; i += blockDim.x) Wl[i] = st[i];
        if (tid < DIM) bl[tid] = st[4096 + tid];
        __syncthreads();
        int f = *flag;
        int wave = tid >> 6, lane = tid & 63;
        int nW = TR_BLOCKS * 4;
        for (int row = tb * 4 + wave; row < N_USERS; row += nW) {
            size_t base = (size_t)row * DIM;
            float v = ld_in(emb, base + lane, f);
            float acc = bl[lane];
#pragma unroll
            for (int k = 0; k < DIM; ++k)
                acc += __shfl(v, k, 64) * Wl[k * DIM + lane];
            h[base + lane] = __float2bfloat16(fmaxf(acc, 0.f));
        }
    } else {
        appendE_body(nodes, hyper, cnt, sn_pad, l8, idx, tid);
    }
}

// ---------------------------------------------------------------------------
// K1(t): ge(t) INTERLEAVED appendN(t); zero(slab t+2) as tail blocks
// ---------------------------------------------------------------------------
__global__ __launch_bounds__(256) void k_ge_appendN(
    const __hip_bfloat16* __restrict__ h,
    const int* __restrict__ sn_pad, const int* __restrict__ cnt_cur,
    __hip_bfloat16* __restrict__ e,
    const int* __restrict__ nodes, const int* __restrict__ hyper,
    int* __restrict__ cnt_w, int* __restrict__ sh_pad,
    int* __restrict__ cnt_zero, int nzero)
{
    int b = blockIdx.x, tid = threadIdx.x;
    if (b >= MAIN_BLKS) {
        if (nzero) zero_body(cnt_zero, b - MAIN_BLKS, tid);
        return;
    }
    int g = b >> 3, l8 = b & 7;
    int role, idx;
    if (g < 2 * GA_GROUPS) { role = g & 1; idx = g >> 1; }
    else { role = 1; idx = g - GA_GROUPS; }

    if (role == 0)
        ge_body(h, sn_pad, cnt_cur, e, idx * 8 + l8, tid);   // >=1563 auto-skips
    else
        appendN_body(nodes, hyper, cnt_w, sh_pad, l8, idx, tid);
}

// ---------------------------------------------------------------------------
// K2(t): gnfuse(t) INTERLEAVED appendE(t+1)
// gnfuse: 16 parallel chains/wave (R5-proven), wave-private LDS strip,
// fuse in-wave. Interleave puts appendE blocks in gnfuse's latency shadow.
// ---------------------------------------------------------------------------
__global__ __launch_bounds__(256) void k_gnfuse(
    const __hip_bfloat16* __restrict__ e,
    const int* __restrict__ sh_pad, const int* __restrict__ cnt_n,
    void* __restrict__ dout, float* __restrict__ cws,
    const float* __restrict__ st, const int* __restrict__ flag,
    int use_ws, int to_carry, int write_out,
    const int* __restrict__ nodes1, const int* __restrict__ hyper1,
    int* __restrict__ cnt_nxt, int* __restrict__ sn_pad, int has_append)
{
    __shared__ float dyl[4 * 16 * 68];   // 4 wave-private strips
    int b = blockIdx.x, tid = threadIdx.x;
    int g = b >> 3, l8 = b & 7;
    int role, idx;
    if (!has_append) { role = 0; idx = g; }
    else if (g < 2 * GA_GROUPS) { role = g & 1; idx = g >> 1; }
    else { role = 1; idx = g - GA_GROUPS; }

    if (role == 0) {
        int gidx = idx * 8 + l8;          // block index in [0,1568)
        int f = *flag;
        int lane = tid & 63, w = tid >> 6;
        int wid  = gidx * 4 + w;
        int row0 = wid * 16;
        if (row0 >= N_USERS) return;

        int pos[16], rem[16], cnt16[16]; float acc[16];
#pragma unroll
        for (int c = 0; c < 16; ++c) {
            int sg = row0 + c;
            int cc = (sg < N_USERS) ? cnt_n[sg] : 0;
            cnt16[c] = cc;
            pos[c]   = sg * CAP_N;
            rem[c]   = min(cc, CAP_N);
            acc[c]   = 0.f;
        }
        while (true) {
            bool any = false;
#pragma unroll
            for (int c = 0; c < 16; ++c) any = any || (rem[c] > 0);
            if (!any) break;
            int hy[16];
#pragma unroll
            for (int c = 0; c < 16; ++c)
                if (rem[c] > 0) hy[c] = sh_pad[pos[c]];
#pragma unroll
            for (int c = 0; c < 16; ++c)
                if (rem[c] > 0) {
                    acc[c] += __bfloat162float(e[(size_t)hy[c] * DIM + lane]);
                    pos[c]++; rem[c]--;
                }
        }
#pragma unroll
        for (int c = 0; c < 16; ++c) {
            int sg = row0 + c;
            if (sg < N_USERS) {
                float v = acc[c] / (float)max(cnt16[c], 1);
                if (to_carry)
                    st_carry(dout, cws, (size_t)sg * DIM + lane, f, use_ws, v);
                else
                    dyl[(w * 16 + c) * 68 + lane] = v;
            }
        }
        if (!to_carry && row0 + 16 <= N_USERS)
            fu_tile(dout, cws, dyl + w * 16 * 68, st, f, use_ws,
                    write_out, row0, tid);
    } else {
        appendE_body(nodes1, hyper1, cnt_nxt, sn_pad, l8, idx, tid);
    }
}

// ---------------------------------------------------------------------------
extern "C" void kernel_launch(void* const* d_in, const int* in_sizes, int n_in,
                              void* d_out, int out_size, void* d_ws,
                              size_t ws_size, hipStream_t stream)
{
    const void* user_emb = d_in[0];
    const void* W_conv   = d_in[1];
    const void* b_conv   = d_in[2];
    const void* fus_w1   = d_in[3];
    const void* fus_b1   = d_in[4];
    const void* fus_w2   = d_in[5];
    const void* fus_b2   = d_in[6];
    const int* edge_nodes = (const int*)d_in[7];
    const int* edge_hyper = (const int*)d_in[8];

    const size_t ND = (size_t)N_USERS * DIM;

    // ws layout (fp32 word offsets) — EXACT R5 proven footprint
    // (mandatory 51.43 MB, with optional carry 77.03 MB):
    //   0         : flag
    //   16        : st [8448]
    //   8464      : counts 3 slabs x 150016 ints (e[0,50K) | n[50K,150K))
    //   458512    : sn_pad int [50000*48]
    //   2858512   : sh_pad int [100000*36]
    //   6458512   : e_buf bf16 [E*D]      (second R5 e_buf slot unused)
    //   9658512   : h bf16 [N*D]
    //   12858512  : optional fp32 carry [N*D]
    float* ws = (float*)d_ws;
    int*   flag   = (int*)ws;
    float* st     = ws + 16;
    int*   cnts[3];
    cnts[0] = (int*)(ws + 8464);
    cnts[1] = (int*)(ws + 8464 + 150016);
    cnts[2] = (int*)(ws + 8464 + 300032);
    int*   sn_pad = (int*)(ws + 458512);
    int*   sh_pad = (int*)(ws + 2858512);
    __hip_bfloat16* e_buf = (__hip_bfloat16*)(ws + 6458512);
    __hip_bfloat16* h     = (__hip_bfloat16*)(ws + 9658512);
    float* carry_ws       = ws + 12858512;

    const size_t need_ws_carry = (12858512 + ND) * 4;
    const int use_ws = (ws_size >= need_ws_carry) ? 1 : 0;

    k_detect<<<1, 256, 0, stream>>>((const unsigned short*)user_emb, flag);
    k_convert_params<<<(8385 + 255) / 256, 256, 0, stream>>>(
        W_conv, b_conv, fus_w1, fus_b1, fus_w2, fus_b2, flag, st);

    // prologue: zero slabs 0,1; transform ⟂ append-E(0)
    k_zero2<<<2 * ZERO_BLKS, 256, 0, stream>>>(cnts[0], cnts[1]);
    k_trans_appendE<<<PRO_BLKS, 256, 0, stream>>>(
        user_emb, flag, st, h, edge_nodes, edge_hyper, cnts[0], sn_pad);

    for (int t = 0; t < T_STEPS; ++t) {
        const int* nodes0 = edge_nodes + (size_t)t * NNZ_E;
        const int* hyper0 = edge_hyper + (size_t)t * NNZ_E;
        const int* nodes1 = edge_nodes + (size_t)(t + 1) * NNZ_E;
        const int* hyper1 = edge_hyper + (size_t)(t + 1) * NNZ_E;
        int c3 = t % 3, n3 = (t + 1) % 3, z3 = (t + 2) % 3;

        // K1: ge(t) ⟂ appendN(t); zero(slab t+2) tail
        int nz = (t < T_STEPS - 2) ? 1 : 0;
        k_ge_appendN<<<MAIN_BLKS + (nz ? ZERO_BLKS : 0), 256, 0, stream>>>(
            h, sn_pad, cnts[c3], e_buf, nodes0, hyper0, cnts[c3], sh_pad,
            cnts[z3], nz);

        // K2: gnfuse(t) ⟂ appendE(t+1)
        int has_append = (t < T_STEPS - 1) ? 1 : 0;
        int grid2 = has_append ? MAIN_BLKS : (GA_GROUPS * 8);
        k_gnfuse<<<grid2, 256, 0, stream>>>(
            e_buf, sh_pad, cnts[c3] + E_HYPER,
            d_out, carry_ws, st, flag, use_ws,
            (t == 0) ? 1 : 0, (t == T_STEPS - 1) ? 1 : 0,
            nodes1, hyper1, cnts[n3], sn_pad, has_append);
    }
}